// Round 4
// 736.505 us; speedup vs baseline: 1.1296x; 1.1296x over previous
//
#include <hip/hip_runtime.h>
#include <math.h>

// Problem constants
#define NU   256      // NUM_UNITS
#define DH   1024     // DIM_HIDDEN
#define NG   8        // NUM_GROUPS
#define BB   768      // BATCH
#define NU4  64       // NU / 4 (float4 units per row)
#define JCH  96       // rows per writer block (BB / 8 chunks)

// clang-native 4-float vector: __builtin_nontemporal_store requires a native
// vector type, not HIP_vector_type<float,4>.
typedef float nfloat4 __attribute__((ext_vector_type(4)));

// ---------------------------------------------------------------------------
// Build X2 = [x ; x_masked]  (1536 x 256)
// ---------------------------------------------------------------------------
__global__ __launch_bounds__(256) void build_x2(const float* __restrict__ x,
                                                const int* __restrict__ mask,
                                                float* __restrict__ X2) {
    int idx = blockIdx.x * 256 + threadIdx.x;     // 0 .. 1536*256-1
    int r = idx >> 8;           // /256
    int c = idx & 255;
    if (r < BB) {
        X2[idx] = x[idx];
    } else {
        int src = (r - BB) * NU + c;
        X2[idx] = mask[src] ? 0.0f : x[src];
    }
}

// ---------------------------------------------------------------------------
// fp32 GEMM + bias (+ optional leaky-relu 0.01): C[M,N] = act(A[M,K]@B[K,N]+b)
// 64x64 tile, 256 threads, 4x4 per thread, BK=16
// ---------------------------------------------------------------------------
__global__ __launch_bounds__(256) void gemm_bias(const float* __restrict__ A,
                                                 const float* __restrict__ B,
                                                 const float* __restrict__ bias,
                                                 float* __restrict__ C,
                                                 int M, int N, int K, int leaky) {
    const int BK = 16;
    __shared__ float As[BK][64 + 1];
    __shared__ float Bs[BK][64];
    int t  = threadIdx.x;
    int tx = t & 15;
    int ty = t >> 4;
    int m0 = blockIdx.y * 64;
    int n0 = blockIdx.x * 64;

    float acc[4][4] = {};

    for (int k0 = 0; k0 < K; k0 += BK) {
        {
            int r = t >> 2;              // 0..63
            int c = (t & 3) * 4;         // 0,4,8,12
            const float4 a = *(const float4*)&A[(size_t)(m0 + r) * K + k0 + c];
            As[c + 0][r] = a.x;
            As[c + 1][r] = a.y;
            As[c + 2][r] = a.z;
            As[c + 3][r] = a.w;
        }
        {
            int r = t >> 4;              // 0..15
            int c = (t & 15) * 4;        // 0..60
            *(float4*)&Bs[r][c] = *(const float4*)&B[(size_t)(k0 + r) * N + n0 + c];
        }
        __syncthreads();
        #pragma unroll
        for (int k = 0; k < BK; ++k) {
            float a[4], b[4];
            #pragma unroll
            for (int q = 0; q < 4; ++q) a[q] = As[k][ty * 4 + q];
            #pragma unroll
            for (int q = 0; q < 4; ++q) b[q] = Bs[k][tx * 4 + q];
            #pragma unroll
            for (int im = 0; im < 4; ++im)
                #pragma unroll
                for (int in = 0; in < 4; ++in)
                    acc[im][in] = fmaf(a[im], b[in], acc[im][in]);
        }
        __syncthreads();
    }

    #pragma unroll
    for (int im = 0; im < 4; ++im) {
        int m = m0 + ty * 4 + im;
        #pragma unroll
        for (int in = 0; in < 4; ++in) {
            int n = n0 + tx * 4 + in;
            float v = acc[im][in] + bias[n];
            if (leaky) v = v > 0.0f ? v : 0.01f * v;
            C[(size_t)m * N + n] = v;
        }
    }
}

// ---------------------------------------------------------------------------
// Stats: per i, scale[i][j2][u] = 0.125 / sum_{j1} exp(-|key[j,u]-query[i,u]|*t[u])
// No max-subtraction: temperature >= 0 -> all logits <= 0 -> exp in (0,1].
// Thread t owns u4 = t&63 (4 units) and row-offset r = t>>6; walking j = r+4k it
// sees exactly groups {r, r+4} -> both group sums fully thread-local (no reduce).
// ---------------------------------------------------------------------------
__global__ __launch_bounds__(256) void stats_kernel(const float* __restrict__ KQ,
                                                    const float* __restrict__ temp,
                                                    float* __restrict__ scale) {
    const int i  = blockIdx.x;          // 0..767
    const int t  = threadIdx.x;
    const int u4 = t & 63;
    const int r  = t >> 6;              // 0..3 (wave-uniform)

    const float4* key4 = (const float4*)KQ;                       // [768][64]
    const float4* qry4 = (const float4*)(KQ + (size_t)BB * NU);   // [768][64]
    const float4 q  = qry4[(size_t)i * NU4 + u4];
    const float4 tp = ((const float4*)temp)[u4];

    float4 sa = make_float4(0.f, 0.f, 0.f, 0.f);   // group r
    float4 sb = make_float4(0.f, 0.f, 0.f, 0.f);   // group r+4

    #pragma unroll 4
    for (int k = 0; k < 192; k += 2) {
        const int jA = r + 4 * k;       // jA % 8 == r
        const int jB = jA + 4;          // jB % 8 == r+4
        const float4 ka = key4[(size_t)jA * NU4 + u4];
        const float4 kb = key4[(size_t)jB * NU4 + u4];
        if (jA != i) {                  // wave-uniform branch (diag -> -inf -> 0)
            sa.x += __expf(-fabsf(ka.x - q.x) * tp.x);
            sa.y += __expf(-fabsf(ka.y - q.y) * tp.y);
            sa.z += __expf(-fabsf(ka.z - q.z) * tp.z);
            sa.w += __expf(-fabsf(ka.w - q.w) * tp.w);
        }
        if (jB != i) {
            sb.x += __expf(-fabsf(kb.x - q.x) * tp.x);
            sb.y += __expf(-fabsf(kb.y - q.y) * tp.y);
            sb.z += __expf(-fabsf(kb.z - q.z) * tp.z);
            sb.w += __expf(-fabsf(kb.w - q.w) * tp.w);
        }
    }

    float4 ia = make_float4(0.125f / sa.x, 0.125f / sa.y, 0.125f / sa.z, 0.125f / sa.w);
    float4 ib = make_float4(0.125f / sb.x, 0.125f / sb.y, 0.125f / sb.z, 0.125f / sb.w);
    ((float4*)scale)[((size_t)i * NG + r) * NU4 + u4]     = ia;
    ((float4*)scale)[((size_t)i * NG + r + 4) * NU4 + u4] = ib;
}

// ---------------------------------------------------------------------------
// Writer: out[i][j][u] = exp(-|key[j,u]-query[i,u]|*t[u]) * scale[i][j%8][u]
// No LDS, no syncthreads. Each wave stores a full contiguous 1 KB row chunk
// (float4/lane x 64 lanes) via nontemporal stores.
// ---------------------------------------------------------------------------
__global__ __launch_bounds__(256) void attn_write(const float* __restrict__ KQ,
                                                  const float* __restrict__ temp,
                                                  const float* __restrict__ scale,
                                                  float* __restrict__ out) {
    const int jc = blockIdx.x;          // 0..7 (96-row chunk)
    const int i  = blockIdx.y;          // 0..767
    const int t  = threadIdx.x;
    const int u4 = t & 63;
    const int r  = t >> 6;              // 0..3 (wave-uniform)
    const int j0 = jc * JCH;            // multiple of 8

    const float4* key4 = (const float4*)KQ;
    const float4* qry4 = (const float4*)(KQ + (size_t)BB * NU);
    const float4 q  = qry4[(size_t)i * NU4 + u4];
    const float4 tp = ((const float4*)temp)[u4];
    // groups this thread touches: j%8 == r (even k) and r+4 (odd k)
    const float4 va = ((const float4*)scale)[((size_t)i * NG + r) * NU4 + u4];
    const float4 vb = ((const float4*)scale)[((size_t)i * NG + r + 4) * NU4 + u4];

    nfloat4* o4 = (nfloat4*)out + (size_t)i * BB * NU4;

    #pragma unroll 4
    for (int k = 0; k < 24; k += 2) {
        const int jA = j0 + r + 4 * k;  // jA % 8 == r
        const int jB = jA + 4;          // jB % 8 == r+4
        const float4 ka = key4[(size_t)jA * NU4 + u4];
        const float4 kb = key4[(size_t)jB * NU4 + u4];
        nfloat4 ea, eb;
        ea.x = __expf(-fabsf(ka.x - q.x) * tp.x) * va.x;
        ea.y = __expf(-fabsf(ka.y - q.y) * tp.y) * va.y;
        ea.z = __expf(-fabsf(ka.z - q.z) * tp.z) * va.z;
        ea.w = __expf(-fabsf(ka.w - q.w) * tp.w) * va.w;
        eb.x = __expf(-fabsf(kb.x - q.x) * tp.x) * vb.x;
        eb.y = __expf(-fabsf(kb.y - q.y) * tp.y) * vb.y;
        eb.z = __expf(-fabsf(kb.z - q.z) * tp.z) * vb.z;
        eb.w = __expf(-fabsf(kb.w - q.w) * tp.w) * vb.w;
        if (jA == i) ea = (nfloat4)0.0f;   // diagonal row -> zeros
        if (jB == i) eb = (nfloat4)0.0f;
        __builtin_nontemporal_store(ea, &o4[(size_t)jA * NU4 + u4]);
        __builtin_nontemporal_store(eb, &o4[(size_t)jB * NU4 + u4]);
    }
}

// ---------------------------------------------------------------------------
// mask -> float epilogue (output 1)
// ---------------------------------------------------------------------------
__global__ __launch_bounds__(256) void mask_out(const int* __restrict__ mask,
                                                float* __restrict__ out) {
    int idx = blockIdx.x * 256 + threadIdx.x;   // 0 .. 768*256-1
    out[idx] = mask[idx] ? 1.0f : 0.0f;
}

// ---------------------------------------------------------------------------
extern "C" void kernel_launch(void* const* d_in, const int* in_sizes, int n_in,
                              void* d_out, int out_size, void* d_ws, size_t ws_size,
                              hipStream_t stream) {
    const float* x    = (const float*)d_in[0];
    const int*   mask = (const int*)d_in[1];
    const float* W1   = (const float*)d_in[2];
    const float* b1   = (const float*)d_in[3];
    const float* W2   = (const float*)d_in[4];
    const float* b2   = (const float*)d_in[5];
    const float* temp = (const float*)d_in[6];
    float* out = (float*)d_out;

    float* ws = (float*)d_ws;
    float* X2 = ws;                                   // 1536*256
    float* H  = X2 + 2 * BB * NU;                     // 1536*1024
    float* KQ = H + 2 * BB * DH;                      // 1536*256
    // scale[768][8][256] reuses H's region: H is dead after the second GEMM,
    // and 768*8*256 == 1536*1024 floats exactly. Zero workspace growth.
    float* scale = H;

    // 1) X2 = [x ; x_masked]
    build_x2<<<dim3(2 * BB * NU / 256), dim3(256), 0, stream>>>(x, mask, X2);

    // 2) H = leaky_relu(X2 @ W1 + b1)   M=1536 N=1024 K=256
    gemm_bias<<<dim3(DH / 64, 2 * BB / 64), dim3(256), 0, stream>>>(
        X2, W1, b1, H, 2 * BB, DH, NU, 1);

    // 3) KQ = H @ W2 + b2               M=1536 N=256 K=1024
    gemm_bias<<<dim3(NU / 64, 2 * BB / 64), dim3(256), 0, stream>>>(
        H, W2, b2, KQ, 2 * BB, NU, DH, 0);

    // 4a) per-(i, group, u) softmax denominators (recompute pass 1)
    stats_kernel<<<dim3(BB), dim3(256), 0, stream>>>(KQ, temp, scale);

    // 4b) streaming writer (recompute pass 2), fully coalesced NT stores
    attn_write<<<dim3(BB / JCH, BB), dim3(256), 0, stream>>>(KQ, temp, scale, out);

    // 5) mask as float (output 1)
    mask_out<<<dim3(BB * NU / 256), dim3(256), 0, stream>>>(
        mask, out + (size_t)BB * BB * NU);
}

// Round 6
// 734.485 us; speedup vs baseline: 1.1327x; 1.0028x over previous
//
#include <hip/hip_runtime.h>
#include <math.h>

// Problem constants
#define NU   256      // NUM_UNITS
#define DH   1024     // DIM_HIDDEN
#define NG   8        // NUM_GROUPS
#define BB   768      // BATCH
#define NU4  64       // NU / 4 (float4 units per row)

// ---------------------------------------------------------------------------
// Build X2 = [x ; x_masked]  (1536 x 256)
// ---------------------------------------------------------------------------
__global__ __launch_bounds__(256) void build_x2(const float* __restrict__ x,
                                                const int* __restrict__ mask,
                                                float* __restrict__ X2) {
    int idx = blockIdx.x * 256 + threadIdx.x;     // 0 .. 1536*256-1
    int r = idx >> 8;           // /256
    int c = idx & 255;
    if (r < BB) {
        X2[idx] = x[idx];
    } else {
        int src = (r - BB) * NU + c;
        X2[idx] = mask[src] ? 0.0f : x[src];
    }
}

// ---------------------------------------------------------------------------
// fp32 GEMM + bias (+ optional leaky-relu 0.01): C[M,N] = act(A[M,K]@B[K,N]+b)
// 64x64 tile, 256 threads, 4x4 per thread, BK=16
// ---------------------------------------------------------------------------
__global__ __launch_bounds__(256) void gemm_bias(const float* __restrict__ A,
                                                 const float* __restrict__ B,
                                                 const float* __restrict__ bias,
                                                 float* __restrict__ C,
                                                 int M, int N, int K, int leaky) {
    const int BK = 16;
    __shared__ float As[BK][64 + 1];
    __shared__ float Bs[BK][64];
    int t  = threadIdx.x;
    int tx = t & 15;
    int ty = t >> 4;
    int m0 = blockIdx.y * 64;
    int n0 = blockIdx.x * 64;

    float acc[4][4] = {};

    for (int k0 = 0; k0 < K; k0 += BK) {
        {
            int r = t >> 2;              // 0..63
            int c = (t & 3) * 4;         // 0,4,8,12
            const float4 a = *(const float4*)&A[(size_t)(m0 + r) * K + k0 + c];
            As[c + 0][r] = a.x;
            As[c + 1][r] = a.y;
            As[c + 2][r] = a.z;
            As[c + 3][r] = a.w;
        }
        {
            int r = t >> 4;              // 0..15
            int c = (t & 15) * 4;        // 0..60
            *(float4*)&Bs[r][c] = *(const float4*)&B[(size_t)(k0 + r) * N + n0 + c];
        }
        __syncthreads();
        #pragma unroll
        for (int k = 0; k < BK; ++k) {
            float a[4], b[4];
            #pragma unroll
            for (int q = 0; q < 4; ++q) a[q] = As[k][ty * 4 + q];
            #pragma unroll
            for (int q = 0; q < 4; ++q) b[q] = Bs[k][tx * 4 + q];
            #pragma unroll
            for (int im = 0; im < 4; ++im)
                #pragma unroll
                for (int in = 0; in < 4; ++in)
                    acc[im][in] = fmaf(a[im], b[in], acc[im][in]);
        }
        __syncthreads();
    }

    #pragma unroll
    for (int im = 0; im < 4; ++im) {
        int m = m0 + ty * 4 + im;
        #pragma unroll
        for (int in = 0; in < 4; ++in) {
            int n = n0 + tx * 4 + in;
            float v = acc[im][in] + bias[n];
            if (leaky) v = v > 0.0f ? v : 0.01f * v;
            C[(size_t)m * N + n] = v;
        }
    }
}

// ---------------------------------------------------------------------------
// Fused softmax-weight kernel. One block per i (768 blocks, 256 threads).
// Thread (r = t>>6, u4 = t&63) owns units u = 4*u4..4*u4+3 and the row set
// {j : j%8 == r} U {j : j%8 == r+4}  — exactly softmax groups r and r+4.
// Pass 1 accumulates both group denominators in registers (no max-sub needed:
// temperature >= 0 -> logits <= 0 -> exp in (0,1], no overflow possible).
// Pass 2 recomputes exp and streams the normalized weights out with plain
// coalesced float4 stores (each wave: 1 KB contiguous per row).
// No LDS, no __syncthreads, no cross-thread communication.
// ---------------------------------------------------------------------------
__global__ __launch_bounds__(256) void attn_fused(const float* __restrict__ KQ,
                                                  const float* __restrict__ temp,
                                                  float* __restrict__ out) {
    const int i  = blockIdx.x;          // 0..767
    const int t  = threadIdx.x;
    const int u4 = t & 63;
    const int r  = t >> 6;              // 0..3 (wave-uniform)

    const float4* key4 = (const float4*)KQ;                       // [768][64]
    const float4* qry4 = (const float4*)(KQ + (size_t)BB * NU);   // [768][64]
    const float4 q  = qry4[(size_t)i * NU4 + u4];
    const float4 tp = ((const float4*)temp)[u4];

    float4 sa = make_float4(0.f, 0.f, 0.f, 0.f);   // group r
    float4 sb = make_float4(0.f, 0.f, 0.f, 0.f);   // group r+4

    // ---- pass 1: denominators ----
    #pragma unroll 4
    for (int m = 0; m < 96; ++m) {
        const int jA = r + 8 * m;       // jA % 8 == r
        const int jB = jA + 4;          // jB % 8 == r+4
        const float4 ka = key4[(size_t)jA * NU4 + u4];
        const float4 kb = key4[(size_t)jB * NU4 + u4];
        if (jA != i) {                  // wave-uniform (diag -> -inf -> 0)
            sa.x += __expf(-fabsf(ka.x - q.x) * tp.x);
            sa.y += __expf(-fabsf(ka.y - q.y) * tp.y);
            sa.z += __expf(-fabsf(ka.z - q.z) * tp.z);
            sa.w += __expf(-fabsf(ka.w - q.w) * tp.w);
        }
        if (jB != i) {
            sb.x += __expf(-fabsf(kb.x - q.x) * tp.x);
            sb.y += __expf(-fabsf(kb.y - q.y) * tp.y);
            sb.z += __expf(-fabsf(kb.z - q.z) * tp.z);
            sb.w += __expf(-fabsf(kb.w - q.w) * tp.w);
        }
    }

    const float4 ia = make_float4(0.125f / sa.x, 0.125f / sa.y,
                                  0.125f / sa.z, 0.125f / sa.w);
    const float4 ib = make_float4(0.125f / sb.x, 0.125f / sb.y,
                                  0.125f / sb.z, 0.125f / sb.w);

    // ---- pass 2: recompute + write ----
    float4* o4 = (float4*)out + (size_t)i * BB * NU4;

    #pragma unroll 2
    for (int m = 0; m < 96; ++m) {
        const int jA = r + 8 * m;
        const int jB = jA + 4;
        const float4 ka = key4[(size_t)jA * NU4 + u4];
        const float4 kb = key4[(size_t)jB * NU4 + u4];
        float4 ea, eb;
        ea.x = __expf(-fabsf(ka.x - q.x) * tp.x) * ia.x;
        ea.y = __expf(-fabsf(ka.y - q.y) * tp.y) * ia.y;
        ea.z = __expf(-fabsf(ka.z - q.z) * tp.z) * ia.z;
        ea.w = __expf(-fabsf(ka.w - q.w) * tp.w) * ia.w;
        eb.x = __expf(-fabsf(kb.x - q.x) * tp.x) * ib.x;
        eb.y = __expf(-fabsf(kb.y - q.y) * tp.y) * ib.y;
        eb.z = __expf(-fabsf(kb.z - q.z) * tp.z) * ib.z;
        eb.w = __expf(-fabsf(kb.w - q.w) * tp.w) * ib.w;
        if (jA == i) ea = make_float4(0.f, 0.f, 0.f, 0.f);   // diagonal row
        if (jB == i) eb = make_float4(0.f, 0.f, 0.f, 0.f);
        o4[(size_t)jA * NU4 + u4] = ea;
        o4[(size_t)jB * NU4 + u4] = eb;
    }
}

// ---------------------------------------------------------------------------
// mask -> float epilogue (output 1)
// ---------------------------------------------------------------------------
__global__ __launch_bounds__(256) void mask_out(const int* __restrict__ mask,
                                                float* __restrict__ out) {
    int idx = blockIdx.x * 256 + threadIdx.x;   // 0 .. 768*256-1
    out[idx] = mask[idx] ? 1.0f : 0.0f;
}

// ---------------------------------------------------------------------------
extern "C" void kernel_launch(void* const* d_in, const int* in_sizes, int n_in,
                              void* d_out, int out_size, void* d_ws, size_t ws_size,
                              hipStream_t stream) {
    const float* x    = (const float*)d_in[0];
    const int*   mask = (const int*)d_in[1];
    const float* W1   = (const float*)d_in[2];
    const float* b1   = (const float*)d_in[3];
    const float* W2   = (const float*)d_in[4];
    const float* b2   = (const float*)d_in[5];
    const float* temp = (const float*)d_in[6];
    float* out = (float*)d_out;

    float* ws = (float*)d_ws;
    float* X2 = ws;                                   // 1536*256
    float* H  = X2 + 2 * BB * NU;                     // 1536*1024
    float* KQ = H + 2 * BB * DH;                      // 1536*256

    // 1) X2 = [x ; x_masked]
    build_x2<<<dim3(2 * BB * NU / 256), dim3(256), 0, stream>>>(x, mask, X2);

    // 2) H = leaky_relu(X2 @ W1 + b1)   M=1536 N=1024 K=256
    gemm_bias<<<dim3(DH / 64, 2 * BB / 64), dim3(256), 0, stream>>>(
        X2, W1, b1, H, 2 * BB, DH, NU, 1);

    // 3) KQ = H @ W2 + b2               M=1536 N=256 K=1024
    gemm_bias<<<dim3(NU / 64, 2 * BB / 64), dim3(256), 0, stream>>>(
        H, W2, b2, KQ, 2 * BB, NU, DH, 0);

    // 4) fused denominators + streaming write (one block per i)
    attn_fused<<<dim3(BB), dim3(256), 0, stream>>>(KQ, temp, out);

    // 5) mask as float (output 1)
    mask_out<<<dim3(BB * NU / 256), dim3(256), 0, stream>>>(
        mask, out + (size_t)BB * BB * NU);
}